// Round 7
// baseline (435.568 us; speedup 1.0000x reference)
//
#include <hip/hip_runtime.h>

// Problem constants
#define B_    16384
#define F_    8
#define L_    16
#define K_    4
#define SEQS_ (B_ * F_)   // 131072

// log2(e) / sqrt(2): folded into Wq/bq at convert time
#define SCORE_SCALE 1.02040774484936f

typedef _Float16 h2  __attribute__((ext_vector_type(2)));
typedef _Float16 h8v __attribute__((ext_vector_type(8)));

#if __has_builtin(__builtin_amdgcn_fdot2)
__device__ __forceinline__ float fdot2(h2 a, h2 b, float c) {
    return __builtin_amdgcn_fdot2(a, b, c, false);   // v_dot2_f32_f16
}
#else
__device__ __forceinline__ float fdot2(h2 a, h2 b, float c) {
    return c + (float)a[0] * (float)b[0] + (float)a[1] * (float)b[1];
}
#endif

__device__ __forceinline__ unsigned pku(float a, float b) {
    return __builtin_bit_cast(unsigned, __builtin_amdgcn_cvt_pkrtz(a, b));
}
__device__ __forceinline__ h2 u2h(unsigned u) {
    return __builtin_bit_cast(h2, u);
}
__device__ __forceinline__ h2 relu2(h2 a) {
#if __has_builtin(__builtin_elementwise_max)
    h2 z = {(_Float16)0.f, (_Float16)0.f};
    return __builtin_elementwise_max(a, z);          // v_pk_max_f16
#else
    h2 r; r[0] = a[0] > (_Float16)0.f ? a[0] : (_Float16)0.f;
          r[1] = a[1] > (_Float16)0.f ? a[1] : (_Float16)0.f;
    return r;
#endif
}

// ---- ws layout (all weights+biases merged -> 1 pointer into seq_kernel) ----
#define WOFF_FW   0
#define WOFF_IPW  16
#define WOFF_OW   304
#define WOFF_L1W  400
#define WOFF_L2W  592
#define NW_U      784
#define BOFF_FB   0
#define BOFF_IPB  8
#define BOFF_OB   80
#define BOFF_L1B  104
#define BOFF_L2B  152
#define BOFF_N1G  176
#define BOFF_N1B  200
#define BOFF_N2G  224
#define BOFF_N2B  248
#define NB_F      272
#define FLOORS_OFF 8192

// ---------------- K0: pack weights fp32 -> h2 pairs, copy biases ----------------
__global__ __launch_bounds__(256) void cvt_weights(
    const float* __restrict__ fw,  const float* __restrict__ ipw,
    const float* __restrict__ ow,  const float* __restrict__ l1w,
    const float* __restrict__ l2w,
    const float* __restrict__ fb,  const float* __restrict__ ipb,
    const float* __restrict__ ob,  const float* __restrict__ l1b,
    const float* __restrict__ l2b,
    const float* __restrict__ n1g, const float* __restrict__ n1b,
    const float* __restrict__ n2g, const float* __restrict__ n2b,
    unsigned* __restrict__ ws)
{
    // weights (pairwise pack; q-rows of ipw get SCORE_SCALE folded in)
    for (int i = threadIdx.x; i < NW_U; i += 256) {
        const float* s; int off; float scale = 1.f;
        if (i < WOFF_IPW)      { s = fw;  off = i; }
        else if (i < WOFF_OW)  { s = ipw; off = i - WOFF_IPW;
                                 if (((off % 96) >> 2) < 8) scale = SCORE_SCALE; }
        else if (i < WOFF_L1W) { s = ow;  off = i - WOFF_OW; }
        else if (i < WOFF_L2W) { s = l1w; off = i - WOFF_L1W; }
        else                   { s = l2w; off = i - WOFF_L2W; }
        ws[i] = pku(s[2*off] * scale, s[2*off + 1] * scale);
    }
    // biases / LN params (fp32 copy; q-rows of ipb scaled)
    float* bias = (float*)(ws + NW_U);
    for (int i = threadIdx.x; i < NB_F; i += 256) {
        float v;
        if (i < BOFF_IPB)      v = fb[i];
        else if (i < BOFF_OB)  { int j = i - BOFF_IPB; v = ipb[j];
                                 if ((j % 24) < 8) v *= SCORE_SCALE; }
        else if (i < BOFF_L1B) v = ob[i - BOFF_OB];
        else if (i < BOFF_L2B) v = l1b[i - BOFF_L1B];
        else if (i < BOFF_N1G) v = l2b[i - BOFF_L2B];
        else if (i < BOFF_N1B) v = n1g[i - BOFF_N1G];
        else if (i < BOFF_N2G) v = n1b[i - BOFF_N1B];
        else if (i < BOFF_N2B) v = n2g[i - BOFF_N2G];
        else                   v = n2b[i - BOFF_N2B];
        bias[i] = v;
    }
}

// ---------------- K1: per-sequence transformer, 2 sequences per group ----------------
// 16 lanes per group, one row each; each group runs TWO sequences (seq, seq+16)
// interleaved for 2x ILP and 2x reuse of every uniform weight s_load.
__global__ __launch_bounds__(256, 6) void seq_kernel(
    const float* __restrict__ gfeats,
    const unsigned* __restrict__ ws)
{
    __shared__ uint4 kb[2][16][17];
    // vt: per (s, group): 68 dwords [jp][d] h2-over-j-pairs + 4 pad.
    __shared__ unsigned vt_dw[2][16 * 68];

    const unsigned* wq  = ws;
    const float* bias   = (const float*)(ws + NW_U);
    h8v* floors_h       = (h8v*)((char*)ws + FLOORS_OFF);

    const int tid = threadIdx.x;
    const int g   = tid >> 4;   // group within block (0..15)
    const int r   = tid & 15;   // row within sequence
    const int seq0 = blockIdx.x * 32 + g;   // s=0
    // s=1 sequence is seq0 + 16

    const int vwr = g*136 + (r>>1)*16 + (r&1);  // halfword write base (per s)
    const int vrd = g*68;                       // dword read base (per s)

    // --- emb_floor: x = feat @ fw.T + fb (both sequences) ---
    float x[2][8];
#pragma unroll
    for (int s = 0; s < 2; ++s) {
        const int seq = seq0 + 16*s;
        const float4 f = *reinterpret_cast<const float4*>(gfeats + ((size_t)seq * L_ + r) * 4);
        const h2 f0 = u2h(pku(f.x, f.y)), f1 = u2h(pku(f.z, f.w));
#pragma unroll
        for (int d = 0; d < 8; ++d)
            x[s][d] = fdot2(f0, u2h(wq[WOFF_FW + d*2]),
                      fdot2(f1, u2h(wq[WOFF_FW + d*2 + 1]), bias[BOFF_FB + d]));
    }

#pragma unroll
    for (int li = 0; li < 3; ++li) {
        const unsigned* W  = wq + WOFF_IPW + li * 96;   // 24 rows x 4 h2
        const float*    Bq = bias + BOFF_IPB + li * 24;

        h2 x2[2][4];
#pragma unroll
        for (int s = 0; s < 2; ++s)
#pragma unroll
            for (int p = 0; p < 4; ++p) x2[s][p] = u2h(pku(x[s][2*p], x[s][2*p+1]));

        // k -> packed fp16 LDS (both s); each s_load of W feeds both sequences
#pragma unroll
        for (int s = 0; s < 2; ++s) {
            float kv[8];
#pragma unroll
            for (int o = 0; o < 8; ++o) {
                const unsigned* w = W + (8 + o)*4;
                float a = Bq[8 + o];
#pragma unroll
                for (int p = 0; p < 4; ++p) a = fdot2(x2[s][p], u2h(w[p]), a);
                kv[o] = a;
            }
            uint4 Kp;
            Kp.x = pku(kv[0], kv[1]); Kp.y = pku(kv[2], kv[3]);
            Kp.z = pku(kv[4], kv[5]); Kp.w = pku(kv[6], kv[7]);
            kb[s][r][g] = Kp;
        }
        // v -> fp16 pair-transposed LDS (halfword scatter, both s)
#pragma unroll
        for (int s = 0; s < 2; ++s) {
            _Float16* vth = (_Float16*)&vt_dw[s][0];
#pragma unroll
            for (int o = 0; o < 8; ++o) {
                const unsigned* w = W + (16 + o)*4;
                float a = Bq[16 + o];
#pragma unroll
                for (int p = 0; p < 4; ++p) a = fdot2(x2[s][p], u2h(w[p]), a);
                vth[vwr + 2*o] = (_Float16)a;
            }
        }
        // q last (scale pre-folded into W/B): hides the k/v write->read gap
        h2 q2[2][4];
#pragma unroll
        for (int s = 0; s < 2; ++s)
#pragma unroll
        for (int h = 0; h < 4; ++h) {
            const unsigned* wa = W + (2*h)*4;
            const unsigned* wb = W + (2*h+1)*4;
            float qa = Bq[2*h], qb = Bq[2*h+1];
#pragma unroll
            for (int p = 0; p < 4; ++p) {
                qa = fdot2(x2[s][p], u2h(wa[p]), qa);
                qb = fdot2(x2[s][p], u2h(wb[p]), qb);
            }
            q2[s][h] = u2h(pku(qa, qb));
        }
        // No __syncthreads: each (s, group) LDS region is wave-private; DS ops
        // are in-order per wave.

        // --- attention over j-pairs, both sequences interleaved ---
        float o_[2][8] = {{0.f,0.f,0.f,0.f,0.f,0.f,0.f,0.f},
                          {0.f,0.f,0.f,0.f,0.f,0.f,0.f,0.f}};
        float sm[2][4] = {{0.f,0.f,0.f,0.f},{0.f,0.f,0.f,0.f}};
        const h2 one2 = u2h(0x3C003C00u);
#pragma unroll
        for (int jp = 0; jp < 8; ++jp) {
#pragma unroll
            for (int s = 0; s < 2; ++s) {
                const uint4 Ka = kb[s][2*jp][g];
                const uint4 Kb = kb[s][2*jp + 1][g];
                const uint4 va = *reinterpret_cast<const uint4*>(&vt_dw[s][vrd + jp*8]);
                const uint4 vb = *reinterpret_cast<const uint4*>(&vt_dw[s][vrd + jp*8 + 4]);
                const float pa0 = __builtin_amdgcn_exp2f(fdot2(q2[s][0], u2h(Ka.x), 0.f));
                const float pa1 = __builtin_amdgcn_exp2f(fdot2(q2[s][1], u2h(Ka.y), 0.f));
                const float pa2 = __builtin_amdgcn_exp2f(fdot2(q2[s][2], u2h(Ka.z), 0.f));
                const float pa3 = __builtin_amdgcn_exp2f(fdot2(q2[s][3], u2h(Ka.w), 0.f));
                const float pb0 = __builtin_amdgcn_exp2f(fdot2(q2[s][0], u2h(Kb.x), 0.f));
                const float pb1 = __builtin_amdgcn_exp2f(fdot2(q2[s][1], u2h(Kb.y), 0.f));
                const float pb2 = __builtin_amdgcn_exp2f(fdot2(q2[s][2], u2h(Kb.z), 0.f));
                const float pb3 = __builtin_amdgcn_exp2f(fdot2(q2[s][3], u2h(Kb.w), 0.f));
                const h2 pp0 = u2h(pku(pa0, pb0));
                const h2 pp1 = u2h(pku(pa1, pb1));
                const h2 pp2 = u2h(pku(pa2, pb2));
                const h2 pp3 = u2h(pku(pa3, pb3));
                sm[s][0] = fdot2(pp0, one2, sm[s][0]);
                sm[s][1] = fdot2(pp1, one2, sm[s][1]);
                sm[s][2] = fdot2(pp2, one2, sm[s][2]);
                sm[s][3] = fdot2(pp3, one2, sm[s][3]);
                o_[s][0] = fdot2(pp0, u2h(va.x), o_[s][0]);
                o_[s][1] = fdot2(pp0, u2h(va.y), o_[s][1]);
                o_[s][2] = fdot2(pp1, u2h(va.z), o_[s][2]);
                o_[s][3] = fdot2(pp1, u2h(va.w), o_[s][3]);
                o_[s][4] = fdot2(pp2, u2h(vb.x), o_[s][4]);
                o_[s][5] = fdot2(pp2, u2h(vb.y), o_[s][5]);
                o_[s][6] = fdot2(pp3, u2h(vb.z), o_[s][6]);
                o_[s][7] = fdot2(pp3, u2h(vb.w), o_[s][7]);
            }
        }

        // --- out-proj + residual + LN1 + FFN + LN2 (per sequence) ---
        const unsigned* OW  = wq + WOFF_OW + li * 32;   // 8 rows x 4 h2
        const float*    OB  = bias + BOFF_OB + li * 8;
        const unsigned* W1  = wq + WOFF_L1W + li * 64;  // 16 rows x 4 h2
        const float*    B1l = bias + BOFF_L1B + li * 16;
        const unsigned* W2  = wq + WOFF_L2W + li * 64;  // 8 rows x 8 h2
        const float*    B2l = bias + BOFF_L2B + li * 8;
        const float* G1 = bias + BOFF_N1G + li * 8;
        const float* C1 = bias + BOFF_N1B + li * 8;
        const float* G2 = bias + BOFF_N2G + li * 8;
        const float* C2 = bias + BOFF_N2B + li * 8;

#pragma unroll
        for (int s = 0; s < 2; ++s) {
            h2 o2[4];
#pragma unroll
            for (int h = 0; h < 4; ++h) {
                const float inv = __builtin_amdgcn_rcpf(sm[s][h]);
                o2[h] = u2h(pku(o_[s][2*h] * inv, o_[s][2*h+1] * inv));
            }
            float y[8];
#pragma unroll
            for (int d = 0; d < 8; ++d) {
                const unsigned* w = OW + d*4;
                float a = OB[d];
#pragma unroll
                for (int p = 0; p < 4; ++p) a = fdot2(o2[p], u2h(w[p]), a);
                y[d] = x[s][d] + a;
            }
            {
                h2 y2[4];
#pragma unroll
                for (int p = 0; p < 4; ++p) y2[p] = u2h(pku(y[2*p], y[2*p+1]));
                float s1 = 0.f, s2 = 0.f;
#pragma unroll
                for (int p = 0; p < 4; ++p) {
                    s1 = fdot2(y2[p], one2, s1);
                    s2 = fdot2(y2[p], y2[p], s2);
                }
                const float m  = s1 * 0.125f;
                const float v  = fmaf(-m, m, s2 * 0.125f);
                const float rs = __builtin_amdgcn_rsqf(v + 1e-5f);
#pragma unroll
                for (int d = 0; d < 8; ++d) x[s][d] = G1[d] * (y[d] - m) * rs + C1[d];
            }
            // FFN
            h2 xx[4];
#pragma unroll
            for (int p = 0; p < 4; ++p) xx[p] = u2h(pku(x[s][2*p], x[s][2*p+1]));
            float hb[16];
#pragma unroll
            for (int o = 0; o < 16; ++o) {
                const unsigned* w = W1 + o*4;
                float a = B1l[o];
#pragma unroll
                for (int p = 0; p < 4; ++p) a = fdot2(xx[p], u2h(w[p]), a);
                hb[o] = a;
            }
            h2 hp[8];
#pragma unroll
            for (int p = 0; p < 8; ++p) hp[p] = relu2(u2h(pku(hb[2*p], hb[2*p+1])));
            float y8[8];
#pragma unroll
            for (int d = 0; d < 8; ++d) {
                const unsigned* w = W2 + d*8;
                float a = B2l[d];
#pragma unroll
                for (int p = 0; p < 8; ++p) a = fdot2(hp[p], u2h(w[p]), a);
                y8[d] = x[s][d] + a;
            }
            {
                h2 y2[4];
#pragma unroll
                for (int p = 0; p < 4; ++p) y2[p] = u2h(pku(y8[2*p], y8[2*p+1]));
                float s1 = 0.f, s2 = 0.f;
#pragma unroll
                for (int p = 0; p < 4; ++p) {
                    s1 = fdot2(y2[p], one2, s1);
                    s2 = fdot2(y2[p], y2[p], s2);
                }
                const float m  = s1 * 0.125f;
                const float v  = fmaf(-m, m, s2 * 0.125f);
                const float rs = __builtin_amdgcn_rsqf(v + 1e-5f);
#pragma unroll
                for (int d = 0; d < 8; ++d) x[s][d] = G2[d] * (y8[d] - m) * rs + C2[d];
            }
        }
    }

    // --- floors[seq] = sum over L (butterfly in 16-lane segment), store fp16 ---
#pragma unroll
    for (int s = 0; s < 2; ++s) {
#pragma unroll
        for (int d = 0; d < 8; ++d) {
            float t = x[s][d];
            t += __shfl_xor(t, 1, 16);
            t += __shfl_xor(t, 2, 16);
            t += __shfl_xor(t, 4, 16);
            t += __shfl_xor(t, 8, 16);
            x[s][d] = t;
        }
        if (r == 0) {
            union { h8v v; unsigned u[4]; } O;
            O.u[0] = pku(x[s][0], x[s][1]); O.u[1] = pku(x[s][2], x[s][3]);
            O.u[2] = pku(x[s][4], x[s][5]); O.u[3] = pku(x[s][6], x[s][7]);
            floors_h[seq0 + 16*s] = O.v;
        }
    }
}

// ---------------- K2: per-batch tail (units + match MLP) ----------------
__global__ __launch_bounds__(64) void tail_kernel(
    const int*   __restrict__ cidxs, const int* __restrict__ slots,
    const float* __restrict__ f2,    const float* __restrict__ f3,
    const float* __restrict__ tab_c, const float* __restrict__ tab_s,
    const float* __restrict__ uw,    const float* __restrict__ ub,
    const float* __restrict__ w1,    const float* __restrict__ b1,
    const float* __restrict__ w2,    const float* __restrict__ b2,
    const h8v*   __restrict__ floors_h, float* __restrict__ out)
{
    const int b = blockIdx.x * 64 + threadIdx.x;
    if (b >= B_) return;

    float units[16];
#pragma unroll
    for (int o = 0; o < 16; ++o) units[o] = 0.f;
    for (int fl_i = 0; fl_i < F_; ++fl_i) {
        union { h8v v; _Float16 s[8]; } U;
        U.v = floors_h[(size_t)b * F_ + fl_i];
        float fl[8];
#pragma unroll
        for (int d = 0; d < 8; ++d) fl[d] = (float)U.s[d];
#pragma unroll
        for (int o = 0; o < 16; ++o) {
            float t = ub[o];
#pragma unroll
            for (int d = 0; d < 8; ++d) t += fl[d] * uw[o*8 + d];
            units[o] += fmaxf(t, 0.f);
        }
    }

    float z36[36];
    {
        const int ci = cidxs[b], si = slots[b];
#pragma unroll
        for (int j = 0; j < 8; ++j) z36[j]     = tab_c[(size_t)ci * 8 + j];
#pragma unroll
        for (int j = 0; j < 8; ++j) z36[8 + j] = tab_s[(size_t)si * 8 + j];
#pragma unroll
        for (int j = 0; j < 16; ++j) z36[16 + j] = units[j];
#pragma unroll
        for (int j = 0; j < 4; ++j) z36[32 + j] = f2[(size_t)b * 4 + j];
    }

    float base[20];
#pragma unroll
    for (int o = 0; o < 20; ++o) {
        float t = b1[o];
#pragma unroll
        for (int j = 0; j < 36; ++j) t += z36[j] * w1[o*42 + j];
        base[o] = t;
    }

    const float bb2 = b2[0];
#pragma unroll
    for (int k = 0; k < K_; ++k) {
        float f3v[6];
#pragma unroll
        for (int j = 0; j < 6; ++j) f3v[j] = f3[((size_t)b * K_ + k) * 6 + j];
        float acc = bb2;
#pragma unroll
        for (int o = 0; o < 20; ++o) {
            float t = base[o];
#pragma unroll
            for (int j = 0; j < 6; ++j) t += f3v[j] * w1[o*42 + 36 + j];
            acc += fmaxf(t, 0.f) * w2[o];
        }
        out[(size_t)b * K_ + k] = acc;
    }

    out[(size_t)(B_ * K_) + b] = 4.0f;   // nf3 = K (d_out read as float32)
}

extern "C" void kernel_launch(void* const* d_in, const int* in_sizes, int n_in,
                              void* d_out, int out_size, void* d_ws, size_t ws_size,
                              hipStream_t stream)
{
    const int*   cidxs  = (const int*)  d_in[0];
    const int*   slots  = (const int*)  d_in[1];
    const float* gfeats = (const float*)d_in[2];
    const float* f2     = (const float*)d_in[3];
    const float* f3     = (const float*)d_in[4];
    const float* tab_c  = (const float*)d_in[5];
    const float* tab_s  = (const float*)d_in[6];
    const float* fw     = (const float*)d_in[7];
    const float* fb     = (const float*)d_in[8];
    const float* ipw    = (const float*)d_in[9];
    const float* ipb    = (const float*)d_in[10];
    const float* ow     = (const float*)d_in[11];
    const float* ob     = (const float*)d_in[12];
    const float* l1w    = (const float*)d_in[13];
    const float* l1b    = (const float*)d_in[14];
    const float* l2w    = (const float*)d_in[15];
    const float* l2b    = (const float*)d_in[16];
    const float* n1g    = (const float*)d_in[17];
    const float* n1b    = (const float*)d_in[18];
    const float* n2g    = (const float*)d_in[19];
    const float* n2b    = (const float*)d_in[20];
    const float* uw     = (const float*)d_in[21];
    const float* ub     = (const float*)d_in[22];
    const float* w1     = (const float*)d_in[23];
    const float* b1     = (const float*)d_in[24];
    const float* w2     = (const float*)d_in[25];
    const float* b2     = (const float*)d_in[26];

    unsigned* ws       = (unsigned*)d_ws;
    h8v*      floors_h = (h8v*)((char*)d_ws + FLOORS_OFF);

    cvt_weights<<<1, 256, 0, stream>>>(fw, ipw, ow, l1w, l2w,
                                       fb, ipb, ob, l1b, l2b,
                                       n1g, n1b, n2g, n2b, ws);

    seq_kernel<<<SEQS_ / 32, 256, 0, stream>>>(gfeats, ws);

    tail_kernel<<<B_ / 64, 64, 0, stream>>>(
        cidxs, slots, f2, f3, tab_c, tab_s, uw, ub, w1, b1, w2, b2,
        floors_h, (float*)d_out);
}

// Round 8
// 181.977 us; speedup vs baseline: 2.3935x; 2.3935x over previous
//
#include <hip/hip_runtime.h>

// Problem constants
#define B_    16384
#define F_    8
#define L_    16
#define K_    4
#define SEQS_ (B_ * F_)   // 131072

// log2(e) / sqrt(2): folded into Wq/bq at convert time
#define SCORE_SCALE 1.02040774484936f

typedef _Float16 h2  __attribute__((ext_vector_type(2)));
typedef _Float16 h8v __attribute__((ext_vector_type(8)));

#if __has_builtin(__builtin_amdgcn_fdot2)
__device__ __forceinline__ float fdot2(h2 a, h2 b, float c) {
    return __builtin_amdgcn_fdot2(a, b, c, false);   // v_dot2_f32_f16
}
#else
__device__ __forceinline__ float fdot2(h2 a, h2 b, float c) {
    return c + (float)a[0] * (float)b[0] + (float)a[1] * (float)b[1];
}
#endif

__device__ __forceinline__ unsigned pku(float a, float b) {
    return __builtin_bit_cast(unsigned, __builtin_amdgcn_cvt_pkrtz(a, b));
}
__device__ __forceinline__ h2 u2h(unsigned u) {
    return __builtin_bit_cast(h2, u);
}
__device__ __forceinline__ h2 relu2(h2 a) {
#if __has_builtin(__builtin_elementwise_max)
    h2 z = {(_Float16)0.f, (_Float16)0.f};
    return __builtin_elementwise_max(a, z);          // v_pk_max_f16
#else
    h2 r; r[0] = a[0] > (_Float16)0.f ? a[0] : (_Float16)0.f;
          r[1] = a[1] > (_Float16)0.f ? a[1] : (_Float16)0.f;
    return r;
#endif
}

// ---- ws layout (all weights+biases merged; staged to LDS in seq_kernel) ----
#define WOFF_FW   0
#define WOFF_IPW  16
#define WOFF_OW   304
#define WOFF_L1W  400
#define WOFF_L2W  592
#define NW_U      784
#define BOFF_FB   0
#define BOFF_IPB  8
#define BOFF_OB   80
#define BOFF_L1B  104
#define BOFF_L2B  152
#define BOFF_N1G  176
#define BOFF_N1B  200
#define BOFF_N2G  224
#define BOFF_N2B  248
#define NB_F      272
#define FLOORS_OFF 8192

// ---------------- K0: pack weights fp32 -> h2 pairs, copy biases ----------------
__global__ __launch_bounds__(256) void cvt_weights(
    const float* __restrict__ fw,  const float* __restrict__ ipw,
    const float* __restrict__ ow,  const float* __restrict__ l1w,
    const float* __restrict__ l2w,
    const float* __restrict__ fb,  const float* __restrict__ ipb,
    const float* __restrict__ ob,  const float* __restrict__ l1b,
    const float* __restrict__ l2b,
    const float* __restrict__ n1g, const float* __restrict__ n1b,
    const float* __restrict__ n2g, const float* __restrict__ n2b,
    unsigned* __restrict__ ws)
{
    // weights (pairwise pack; q-rows of ipw get SCORE_SCALE folded in)
    for (int i = threadIdx.x; i < NW_U; i += 256) {
        const float* s; int off; float scale = 1.f;
        if (i < WOFF_IPW)      { s = fw;  off = i; }
        else if (i < WOFF_OW)  { s = ipw; off = i - WOFF_IPW;
                                 if (((off % 96) >> 2) < 8) scale = SCORE_SCALE; }
        else if (i < WOFF_L1W) { s = ow;  off = i - WOFF_OW; }
        else if (i < WOFF_L2W) { s = l1w; off = i - WOFF_L1W; }
        else                   { s = l2w; off = i - WOFF_L2W; }
        ws[i] = pku(s[2*off] * scale, s[2*off + 1] * scale);
    }
    // biases / LN params (fp32 copy; q-rows of ipb scaled)
    float* bias = (float*)(ws + NW_U);
    for (int i = threadIdx.x; i < NB_F; i += 256) {
        float v;
        if (i < BOFF_IPB)      v = fb[i];
        else if (i < BOFF_OB)  { int j = i - BOFF_IPB; v = ipb[j];
                                 if ((j % 24) < 8) v *= SCORE_SCALE; }
        else if (i < BOFF_L1B) v = ob[i - BOFF_OB];
        else if (i < BOFF_L2B) v = l1b[i - BOFF_L1B];
        else if (i < BOFF_N1G) v = l2b[i - BOFF_L2B];
        else if (i < BOFF_N1B) v = n1g[i - BOFF_N1G];
        else if (i < BOFF_N2G) v = n1b[i - BOFF_N1B];
        else if (i < BOFF_N2B) v = n2g[i - BOFF_N2G];
        else                   v = n2b[i - BOFF_N2B];
        bias[i] = v;
    }
}

// ---------------- K1: per-sequence transformer ----------------
// 16 lanes per sequence (one row each), 16 sequences per 256-thread block.
// Weights+biases staged to LDS once per block: weight fetches become
// VGPR-buffered ds_reads (deep pipelining) instead of SGPR-starved s_loads.
__global__ __launch_bounds__(256, 8) void seq_kernel(
    const float* __restrict__ gfeats,
    const unsigned* __restrict__ ws)
{
    __shared__ uint4 kb[16][17];
    // vt: per group 68 dwords ([jp][d] h2-over-j-pairs + 4 pad).
    __shared__ unsigned vt_dw[16 * 68];
    // staged weights + biases (uniform; broadcast reads, 0 conflicts)
    __shared__ unsigned wlds[NW_U + NB_F];

    for (int i = threadIdx.x; i < NW_U + NB_F; i += 256) wlds[i] = ws[i];
    __syncthreads();

    const unsigned* wq  = wlds;
    const float* bias   = (const float*)(wlds + NW_U);
    h8v* floors_h       = (h8v*)((char*)ws + FLOORS_OFF);

    const int tid = threadIdx.x;
    const int g   = tid >> 4;   // group within block (0..15)
    const int r   = tid & 15;   // row within sequence
    const int seq = blockIdx.x * 16 + g;

    _Float16* vth = (_Float16*)vt_dw;
    const int vwr = g*136 + (r>>1)*16 + (r&1);  // halfword write base
    const int vrd = g*68;                       // dword read base

    // --- emb_floor: x = feat @ fw.T + fb ---
    const float4 f = *reinterpret_cast<const float4*>(gfeats + ((size_t)seq * L_ + r) * 4);
    const h2 f0 = u2h(pku(f.x, f.y)), f1 = u2h(pku(f.z, f.w));
    float x[8];
#pragma unroll
    for (int d = 0; d < 8; ++d)
        x[d] = fdot2(f0, u2h(wq[WOFF_FW + d*2]),
               fdot2(f1, u2h(wq[WOFF_FW + d*2 + 1]), bias[BOFF_FB + d]));

#pragma unroll
    for (int li = 0; li < 3; ++li) {
        const unsigned* W  = wq + WOFF_IPW + li * 96;   // 24 rows x 4 h2
        const float*    Bq = bias + BOFF_IPB + li * 24;

        h2 x2[4];
#pragma unroll
        for (int p = 0; p < 4; ++p) x2[p] = u2h(pku(x[2*p], x[2*p+1]));

        // k -> packed fp16 LDS (issued first so write->read latency is hidden
        // by the v and q computations below)
        {
            float kv[8];
#pragma unroll
            for (int o = 0; o < 8; ++o) {
                const unsigned* w = W + (8 + o)*4;
                float a = Bq[8 + o];
#pragma unroll
                for (int p = 0; p < 4; ++p) a = fdot2(x2[p], u2h(w[p]), a);
                kv[o] = a;
            }
            uint4 K;
            K.x = pku(kv[0], kv[1]); K.y = pku(kv[2], kv[3]);
            K.z = pku(kv[4], kv[5]); K.w = pku(kv[6], kv[7]);
            kb[r][g] = K;
        }
        // v -> fp16 pair-transposed LDS (halfword scatter)
        {
#pragma unroll
            for (int o = 0; o < 8; ++o) {
                const unsigned* w = W + (16 + o)*4;
                float a = Bq[16 + o];
#pragma unroll
                for (int p = 0; p < 4; ++p) a = fdot2(x2[p], u2h(w[p]), a);
                vth[vwr + 2*o] = (_Float16)a;
            }
        }
        // q last (scale pre-folded into W/B): hides the v write->read gap
        h2 q2[4];
#pragma unroll
        for (int h = 0; h < 4; ++h) {
            const unsigned* wa = W + (2*h)*4;
            const unsigned* wb = W + (2*h+1)*4;
            float qa = Bq[2*h], qb = Bq[2*h+1];
#pragma unroll
            for (int p = 0; p < 4; ++p) {
                qa = fdot2(x2[p], u2h(wa[p]), qa);
                qb = fdot2(x2[p], u2h(wb[p]), qb);
            }
            q2[h] = u2h(pku(qa, qb));
        }
        // Group's k/v LDS region is wave-private; DS ops are in-order per wave
        // (the only barrier is the weight staging at kernel start).

        // --- attention over j-pairs, depth-1 software prefetch ---
        float o_[8] = {0.f,0.f,0.f,0.f,0.f,0.f,0.f,0.f};
        float sm[4] = {0.f,0.f,0.f,0.f};
        const h2 one2 = u2h(0x3C003C00u);

        uint4 cKa = kb[0][g];
        uint4 cKb = kb[1][g];
        uint4 cva = *reinterpret_cast<const uint4*>(&vt_dw[vrd]);
        uint4 cvb = *reinterpret_cast<const uint4*>(&vt_dw[vrd + 4]);
#pragma unroll
        for (int jp = 0; jp < 8; ++jp) {
            uint4 nKa, nKb, nva, nvb;
            if (jp < 7) {
                nKa = kb[2*jp + 2][g];
                nKb = kb[2*jp + 3][g];
                nva = *reinterpret_cast<const uint4*>(&vt_dw[vrd + (jp+1)*8]);
                nvb = *reinterpret_cast<const uint4*>(&vt_dw[vrd + (jp+1)*8 + 4]);
            }
            const float pa0 = __builtin_amdgcn_exp2f(fdot2(q2[0], u2h(cKa.x), 0.f));
            const float pa1 = __builtin_amdgcn_exp2f(fdot2(q2[1], u2h(cKa.y), 0.f));
            const float pa2 = __builtin_amdgcn_exp2f(fdot2(q2[2], u2h(cKa.z), 0.f));
            const float pa3 = __builtin_amdgcn_exp2f(fdot2(q2[3], u2h(cKa.w), 0.f));
            const float pb0 = __builtin_amdgcn_exp2f(fdot2(q2[0], u2h(cKb.x), 0.f));
            const float pb1 = __builtin_amdgcn_exp2f(fdot2(q2[1], u2h(cKb.y), 0.f));
            const float pb2 = __builtin_amdgcn_exp2f(fdot2(q2[2], u2h(cKb.z), 0.f));
            const float pb3 = __builtin_amdgcn_exp2f(fdot2(q2[3], u2h(cKb.w), 0.f));
            const h2 pp0 = u2h(pku(pa0, pb0));
            const h2 pp1 = u2h(pku(pa1, pb1));
            const h2 pp2 = u2h(pku(pa2, pb2));
            const h2 pp3 = u2h(pku(pa3, pb3));
            sm[0] = fdot2(pp0, one2, sm[0]);
            sm[1] = fdot2(pp1, one2, sm[1]);
            sm[2] = fdot2(pp2, one2, sm[2]);
            sm[3] = fdot2(pp3, one2, sm[3]);
            o_[0] = fdot2(pp0, u2h(cva.x), o_[0]);
            o_[1] = fdot2(pp0, u2h(cva.y), o_[1]);
            o_[2] = fdot2(pp1, u2h(cva.z), o_[2]);
            o_[3] = fdot2(pp1, u2h(cva.w), o_[3]);
            o_[4] = fdot2(pp2, u2h(cvb.x), o_[4]);
            o_[5] = fdot2(pp2, u2h(cvb.y), o_[5]);
            o_[6] = fdot2(pp3, u2h(cvb.z), o_[6]);
            o_[7] = fdot2(pp3, u2h(cvb.w), o_[7]);
            cKa = nKa; cKb = nKb; cva = nva; cvb = nvb;
        }

        // --- out-proj + residual + LN1 (1/sum folded into o2 pack) ---
        const unsigned* OW = wq + WOFF_OW + li * 32;   // 8 rows x 4 h2
        const float*    OB = bias + BOFF_OB + li * 8;
        h2 o2[4];
#pragma unroll
        for (int h = 0; h < 4; ++h) {
            const float inv = __builtin_amdgcn_rcpf(sm[h]);
            o2[h] = u2h(pku(o_[2*h] * inv, o_[2*h+1] * inv));
        }
        float y[8];
#pragma unroll
        for (int d = 0; d < 8; ++d) {
            const unsigned* w = OW + d*4;
            float a = OB[d];
#pragma unroll
            for (int p = 0; p < 4; ++p) a = fdot2(o2[p], u2h(w[p]), a);
            y[d] = x[d] + a;
        }
        {
            const float* G  = bias + BOFF_N1G + li * 8;
            const float* Bb = bias + BOFF_N1B + li * 8;
            // stats via packed dots: m = Sum(y)/8, var = Sum(y^2)/8 - m^2
            h2 y2[4];
#pragma unroll
            for (int p = 0; p < 4; ++p) y2[p] = u2h(pku(y[2*p], y[2*p+1]));
            float s1 = 0.f, s2 = 0.f;
#pragma unroll
            for (int p = 0; p < 4; ++p) {
                s1 = fdot2(y2[p], one2, s1);
                s2 = fdot2(y2[p], y2[p], s2);
            }
            const float m  = s1 * 0.125f;
            const float v  = fmaf(-m, m, s2 * 0.125f);
            const float rs = __builtin_amdgcn_rsqf(v + 1e-5f);
#pragma unroll
            for (int d = 0; d < 8; ++d) x[d] = G[d] * (y[d] - m) * rs + Bb[d];
        }

        // --- FFN (8->16->8, relu) + residual + LN2 ---
        const unsigned* W1  = wq + WOFF_L1W + li * 64;  // 16 rows x 4 h2
        const float*    B1l = bias + BOFF_L1B + li * 16;
        const unsigned* W2  = wq + WOFF_L2W + li * 64;  // 8 rows x 8 h2
        const float*    B2l = bias + BOFF_L2B + li * 8;
#pragma unroll
        for (int p = 0; p < 4; ++p) x2[p] = u2h(pku(x[2*p], x[2*p+1]));
        float hb[16];
#pragma unroll
        for (int o = 0; o < 16; ++o) {
            const unsigned* w = W1 + o*4;
            float a = B1l[o];
#pragma unroll
            for (int p = 0; p < 4; ++p) a = fdot2(x2[p], u2h(w[p]), a);
            hb[o] = a;
        }
        h2 hp[8];
#pragma unroll
        for (int p = 0; p < 8; ++p) hp[p] = relu2(u2h(pku(hb[2*p], hb[2*p+1])));
        float y8[8];
#pragma unroll
        for (int d = 0; d < 8; ++d) {
            const unsigned* w = W2 + d*8;
            float a = B2l[d];
#pragma unroll
            for (int p = 0; p < 8; ++p) a = fdot2(hp[p], u2h(w[p]), a);
            y8[d] = x[d] + a;
        }
        {
            const float* G  = bias + BOFF_N2G + li * 8;
            const float* Bb = bias + BOFF_N2B + li * 8;
            h2 y2[4];
#pragma unroll
            for (int p = 0; p < 4; ++p) y2[p] = u2h(pku(y8[2*p], y8[2*p+1]));
            float s1 = 0.f, s2 = 0.f;
#pragma unroll
            for (int p = 0; p < 4; ++p) {
                s1 = fdot2(y2[p], one2, s1);
                s2 = fdot2(y2[p], y2[p], s2);
            }
            const float m  = s1 * 0.125f;
            const float v  = fmaf(-m, m, s2 * 0.125f);
            const float rs = __builtin_amdgcn_rsqf(v + 1e-5f);
#pragma unroll
            for (int d = 0; d < 8; ++d) x[d] = G[d] * (y8[d] - m) * rs + Bb[d];
        }
    }

    // --- floors[seq] = sum over L (butterfly in 16-lane segment), store fp16 ---
#pragma unroll
    for (int d = 0; d < 8; ++d) {
        float t = x[d];
        t += __shfl_xor(t, 1, 16);
        t += __shfl_xor(t, 2, 16);
        t += __shfl_xor(t, 4, 16);
        t += __shfl_xor(t, 8, 16);
        x[d] = t;
    }
    if (r == 0) {
        union { h8v v; unsigned u[4]; } O;
        O.u[0] = pku(x[0], x[1]); O.u[1] = pku(x[2], x[3]);
        O.u[2] = pku(x[4], x[5]); O.u[3] = pku(x[6], x[7]);
        floors_h[seq] = O.v;
    }
}

// ---------------- K2: per-batch tail (units + match MLP) ----------------
__global__ __launch_bounds__(64) void tail_kernel(
    const int*   __restrict__ cidxs, const int* __restrict__ slots,
    const float* __restrict__ f2,    const float* __restrict__ f3,
    const float* __restrict__ tab_c, const float* __restrict__ tab_s,
    const float* __restrict__ uw,    const float* __restrict__ ub,
    const float* __restrict__ w1,    const float* __restrict__ b1,
    const float* __restrict__ w2,    const float* __restrict__ b2,
    const h8v*   __restrict__ floors_h, float* __restrict__ out)
{
    const int b = blockIdx.x * 64 + threadIdx.x;
    if (b >= B_) return;

    float units[16];
#pragma unroll
    for (int o = 0; o < 16; ++o) units[o] = 0.f;
    for (int fl_i = 0; fl_i < F_; ++fl_i) {
        union { h8v v; _Float16 s[8]; } U;
        U.v = floors_h[(size_t)b * F_ + fl_i];
        float fl[8];
#pragma unroll
        for (int d = 0; d < 8; ++d) fl[d] = (float)U.s[d];
#pragma unroll
        for (int o = 0; o < 16; ++o) {
            float t = ub[o];
#pragma unroll
            for (int d = 0; d < 8; ++d) t += fl[d] * uw[o*8 + d];
            units[o] += fmaxf(t, 0.f);
        }
    }

    float z36[36];
    {
        const int ci = cidxs[b], si = slots[b];
#pragma unroll
        for (int j = 0; j < 8; ++j) z36[j]     = tab_c[(size_t)ci * 8 + j];
#pragma unroll
        for (int j = 0; j < 8; ++j) z36[8 + j] = tab_s[(size_t)si * 8 + j];
#pragma unroll
        for (int j = 0; j < 16; ++j) z36[16 + j] = units[j];
#pragma unroll
        for (int j = 0; j < 4; ++j) z36[32 + j] = f2[(size_t)b * 4 + j];
    }

    float base[20];
#pragma unroll
    for (int o = 0; o < 20; ++o) {
        float t = b1[o];
#pragma unroll
        for (int j = 0; j < 36; ++j) t += z36[j] * w1[o*42 + j];
        base[o] = t;
    }

    const float bb2 = b2[0];
#pragma unroll
    for (int k = 0; k < K_; ++k) {
        float f3v[6];
#pragma unroll
        for (int j = 0; j < 6; ++j) f3v[j] = f3[((size_t)b * K_ + k) * 6 + j];
        float acc = bb2;
#pragma unroll
        for (int o = 0; o < 20; ++o) {
            float t = base[o];
#pragma unroll
            for (int j = 0; j < 6; ++j) t += f3v[j] * w1[o*42 + 36 + j];
            acc += fmaxf(t, 0.f) * w2[o];
        }
        out[(size_t)b * K_ + k] = acc;
    }

    out[(size_t)(B_ * K_) + b] = 4.0f;   // nf3 = K (d_out read as float32)
}

extern "C" void kernel_launch(void* const* d_in, const int* in_sizes, int n_in,
                              void* d_out, int out_size, void* d_ws, size_t ws_size,
                              hipStream_t stream)
{
    const int*   cidxs  = (const int*)  d_in[0];
    const int*   slots  = (const int*)  d_in[1];
    const float* gfeats = (const float*)d_in[2];
    const float* f2     = (const float*)d_in[3];
    const float* f3     = (const float*)d_in[4];
    const float* tab_c  = (const float*)d_in[5];
    const float* tab_s  = (const float*)d_in[6];
    const float* fw     = (const float*)d_in[7];
    const float* fb     = (const float*)d_in[8];
    const float* ipw    = (const float*)d_in[9];
    const float* ipb    = (const float*)d_in[10];
    const float* ow     = (const float*)d_in[11];
    const float* ob     = (const float*)d_in[12];
    const float* l1w    = (const float*)d_in[13];
    const float* l1b    = (const float*)d_in[14];
    const float* l2w    = (const float*)d_in[15];
    const float* l2b    = (const float*)d_in[16];
    const float* n1g    = (const float*)d_in[17];
    const float* n1b    = (const float*)d_in[18];
    const float* n2g    = (const float*)d_in[19];
    const float* n2b    = (const float*)d_in[20];
    const float* uw     = (const float*)d_in[21];
    const float* ub     = (const float*)d_in[22];
    const float* w1     = (const float*)d_in[23];
    const float* b1     = (const float*)d_in[24];
    const float* w2     = (const float*)d_in[25];
    const float* b2     = (const float*)d_in[26];

    unsigned* ws       = (unsigned*)d_ws;
    h8v*      floors_h = (h8v*)((char*)d_ws + FLOORS_OFF);

    cvt_weights<<<1, 256, 0, stream>>>(fw, ipw, ow, l1w, l2w,
                                       fb, ipb, ob, l1b, l2b,
                                       n1g, n1b, n2g, n2b, ws);

    seq_kernel<<<SEQS_ / 16, 256, 0, stream>>>(gfeats, ws);

    tail_kernel<<<B_ / 64, 64, 0, stream>>>(
        cidxs, slots, f2, f3, tab_c, tab_s, uw, ub, w1, b1, w2, b2,
        floors_h, (float*)d_out);
}